// Round 1
// baseline (8574.970 us; speedup 1.0000x reference)
//
#include <hip/hip_runtime.h>
#include <hip/hip_bf16.h>
#include <cstddef>

// Problem constants (fixed by the reference)
#define NN 8160     // encoder rows
#define MM 8160     // decoder rows
#define HH 128      // hidden
#define NCLS 80

// ---------------------------------------------------------------------------
// Generic GEMM: C[m,n] = act(dot(A[m,0:K], W[n,0:K]) + bias[n])
// A: [M,K] rows stride lda. W: [N,K] row-major (ld=K). C stride ldc.
// Requirements: K % 32 == 0, N % 64 == 0. M guarded.
// ---------------------------------------------------------------------------
template<bool RELU>
__global__ __launch_bounds__(256) void gemm_nt(
    const float* __restrict__ A, int lda,
    const float* __restrict__ W, const float* __restrict__ bias,
    float* __restrict__ C, int ldc,
    int M, int N, int K)
{
    __shared__ __align__(16) float As[64][36];   // [m][k], padded stride 36
    __shared__ __align__(16) float Wt[32][68];   // [k][n], padded stride 68

    const int tid = threadIdx.x;
    const int tx = tid & 15, ty = tid >> 4;
    const int m0 = blockIdx.x * 64, n0 = blockIdx.y * 64;
    const int lr = tid >> 3;     // 0..31
    const int lc = tid & 7;      // float4 col 0..7 (k = lc*4)

    float acc[4][4] = {};

    for (int k0 = 0; k0 < K; k0 += 32) {
        // stage A tile (rows guarded)
        #pragma unroll
        for (int rr = 0; rr < 2; rr++) {
            int r = lr + rr * 32;
            int gm = m0 + r;
            float4 v = make_float4(0.f, 0.f, 0.f, 0.f);
            if (gm < M) v = *(const float4*)&A[(size_t)gm * lda + k0 + lc * 4];
            *(float4*)&As[r][lc * 4] = v;
        }
        // stage W tile transposed: Wt[k][n]
        #pragma unroll
        for (int rr = 0; rr < 2; rr++) {
            int r = lr + rr * 32;  // n-local
            float4 v = *(const float4*)&W[(size_t)(n0 + r) * K + k0 + lc * 4];
            Wt[lc * 4 + 0][r] = v.x;
            Wt[lc * 4 + 1][r] = v.y;
            Wt[lc * 4 + 2][r] = v.z;
            Wt[lc * 4 + 3][r] = v.w;
        }
        __syncthreads();

        #pragma unroll
        for (int k4 = 0; k4 < 8; k4++) {
            float4 a4[4], w4[4];
            #pragma unroll
            for (int i = 0; i < 4; i++)
                a4[i] = *(const float4*)&As[ty * 4 + i][k4 * 4];
            #pragma unroll
            for (int kk = 0; kk < 4; kk++)
                w4[kk] = *(const float4*)&Wt[k4 * 4 + kk][tx * 4];
            #pragma unroll
            for (int i = 0; i < 4; i++) {
                acc[i][0] += a4[i].x * w4[0].x + a4[i].y * w4[1].x + a4[i].z * w4[2].x + a4[i].w * w4[3].x;
                acc[i][1] += a4[i].x * w4[0].y + a4[i].y * w4[1].y + a4[i].z * w4[2].y + a4[i].w * w4[3].y;
                acc[i][2] += a4[i].x * w4[0].z + a4[i].y * w4[1].z + a4[i].z * w4[2].z + a4[i].w * w4[3].z;
                acc[i][3] += a4[i].x * w4[0].w + a4[i].y * w4[1].w + a4[i].z * w4[2].w + a4[i].w * w4[3].w;
            }
        }
        __syncthreads();
    }

    #pragma unroll
    for (int i = 0; i < 4; i++) {
        int gm = m0 + ty * 4 + i;
        if (gm >= M) continue;
        #pragma unroll
        for (int j = 0; j < 4; j++) {
            int gn = n0 + tx * 4 + j;
            float v = acc[i][j] + bias[gn];
            if (RELU) v = v > 0.f ? v : 0.f;
            C[(size_t)gm * ldc + gn] = v;
        }
    }
}

// ---------------------------------------------------------------------------
// Copy all_class score/box into columns [128,192) of dec_cat (ld 192).
// ---------------------------------------------------------------------------
__global__ void copy_scorebox(const float* __restrict__ acs,
                              const float* __restrict__ acb,
                              float* __restrict__ cat, int M)
{
    int i = blockIdx.x * blockDim.x + threadIdx.x;
    if (i >= M * 64) return;
    int m = i >> 6, c = i & 63;
    float v = (c < 32) ? acs[m * 32 + c] : acb[m * 32 + (c - 32)];
    cat[(size_t)m * 192 + 128 + c] = v;
}

// ---------------------------------------------------------------------------
// Sequential GRU (PyTorch gate semantics), batch=1.
// 768 threads: gate-row grow = t>>1 (0..383), half = t&1 handles 64 of the
// 128 k's; pair-reduce via shfl_xor(1). Whh row halves live in registers.
// enc mode: seglen==nullptr, grid=2 (dir), h0=0, writes h_final only.
// dec mode: seglen!=nullptr, grid=160 ((seg,dir)), h0=h_init[dir], writes ys.
// gx layout: row stride gx_ld, forward gates at gx_f, backward at gx_b.
// ---------------------------------------------------------------------------
__global__ __launch_bounds__(768) void gru_seq(
    const float* __restrict__ gx_f, const float* __restrict__ gx_b, int gx_ld,
    const float* __restrict__ Whh,   // [2,384,128]
    const float* __restrict__ bhh,   // [2,384]
    const int*   __restrict__ seglen,
    const float* __restrict__ h_init,  // [2,128] or null (zeros)
    float* __restrict__ h_final,       // [2,128] or null
    float* __restrict__ ys_f, float* __restrict__ ys_b,  // [M,128] or null
    int M)
{
    int dir, start, end;
    if (seglen) {
        dir = blockIdx.x & 1;
        int seg = blockIdx.x >> 1;
        start = seglen[seg];
        end = seglen[seg + 1];
    } else {
        dir = blockIdx.x;
        start = 0;
        end = M;
    }
    const int T = end - start;
    const float* gx = dir ? gx_b : gx_f;
    float* ys = dir ? ys_b : ys_f;

    const int t = threadIdx.x;
    const int grow = t >> 1;        // 0..383
    const int half = t & 1;
    const int j = grow & 127;
    const int gt = grow >> 7;       // 0=r, 1=z, 2=n

    __shared__ __align__(16) float h_s[128];
    __shared__ float rg_s[128], z_s[128];

    // load Whh row half into registers (64 f32)
    float4 w4[16];
    const float* wrow = Whh + ((size_t)dir * 384 + grow) * 128 + half * 64;
    #pragma unroll
    for (int kk = 0; kk < 16; kk++) w4[kk] = *(const float4*)&wrow[kk * 4];
    const float bh = bhh[dir * 384 + grow];

    if (t < 128) h_s[t] = h_init ? h_init[dir * 128 + t] : 0.f;
    __syncthreads();
    if (T <= 0) return;

    const int trow0 = dir ? (end - 1) : start;
    float gxv = gx[(size_t)trow0 * gx_ld + grow];

    for (int s = 0; s < T; s++) {
        const int sn = (s + 1 < T) ? s + 1 : s;
        const int trow  = dir ? (end - 1 - s)  : (start + s);
        const int trown = dir ? (end - 1 - sn) : (start + sn);
        const float gx_next = gx[(size_t)trown * gx_ld + grow];  // prefetch

        // matvec half: dot(h[half*64 .. +64), w)
        float a0 = 0.f, a1 = 0.f, a2 = 0.f, a3 = 0.f;
        const float4* h4 = (const float4*)h_s + half * 16;
        #pragma unroll
        for (int kk = 0; kk < 16; kk++) {
            float4 hv = h4[kk];
            a0 += w4[kk].x * hv.x;
            a1 += w4[kk].y * hv.y;
            a2 += w4[kk].z * hv.z;
            a3 += w4[kk].w * hv.w;
        }
        float acc = (a0 + a1) + (a2 + a3);
        acc += __shfl_xor(acc, 1, 64);   // pair (2g, 2g+1) full dot

        const float hn_pre = acc + bh;   // h@Whh.T + bhh   (no gx)
        const float pre = hn_pre + gxv;

        if (gt == 0) {
            if (!half) rg_s[j] = 1.f / (1.f + __expf(-pre));
        } else if (gt == 1) {
            if (!half) z_s[j] = 1.f / (1.f + __expf(-pre));
        }
        __syncthreads();

        if (gt == 2 && !half) {
            const float rg = rg_s[j], z = z_s[j];
            const float narg = gxv + rg * hn_pre;
            const float n = 1.f - 2.f / (1.f + __expf(2.f * narg));  // tanh
            const float hnew = (1.f - z) * n + z * h_s[j];
            h_s[j] = hnew;
            if (ys) ys[(size_t)trow * 128 + j] = hnew;
        }
        __syncthreads();
        gxv = gx_next;
    }

    if (h_final && t < 128) h_final[dir * 128 + t] = h_s[t];
}

// ---------------------------------------------------------------------------
// out[m] = sigmoid(dot(ys_f[m], ow[0:128]) + dot(ys_b[m], ow[128:256]) + ob)
// ---------------------------------------------------------------------------
__global__ __launch_bounds__(64) void out_kernel(
    const float* __restrict__ ysf, const float* __restrict__ ysb,
    const float* __restrict__ ow, const float* __restrict__ ob,
    float* __restrict__ out, int M)
{
    const int m = blockIdx.x;
    const int l = threadIdx.x;  // 0..63
    const float* f = ysf + (size_t)m * 128;
    const float* b = ysb + (size_t)m * 128;
    float s = f[l] * ow[l] + f[l + 64] * ow[l + 64]
            + b[l] * ow[128 + l] + b[l + 64] * ow[192 + l];
    #pragma unroll
    for (int o = 32; o >= 1; o >>= 1) s += __shfl_xor(s, o, 64);
    if (l == 0) out[m] = 1.f / (1.f + __expf(-(s + ob[0])));
}

// ---------------------------------------------------------------------------
extern "C" void kernel_launch(void* const* d_in, const int* in_sizes, int n_in,
                              void* d_out, int out_size, void* d_ws, size_t ws_size,
                              hipStream_t stream)
{
    // inputs (setup_inputs dict order)
    const float* boxes_feature = (const float*)d_in[0];   // [N,1024]
    const float* boxes_score   = (const float*)d_in[1];   // [N,2560]
    const float* boxes_box     = (const float*)d_in[2];   // [N,320]
    const float* ac_feature    = (const float*)d_in[3];   // [M,1024]
    const float* ac_score      = (const float*)d_in[4];   // [M,32]
    const float* ac_box        = (const float*)d_in[5];   // [M,32]
    const int*   ucl           = (const int*)d_in[7];     // [81]
    const float* appear_W = (const float*)d_in[8];
    const float* appear_b = (const float*)d_in[9];
    const float* s1_W = (const float*)d_in[10];
    const float* s1_b = (const float*)d_in[11];
    const float* s2_W = (const float*)d_in[12];
    const float* s2_b = (const float*)d_in[13];
    const float* box_W = (const float*)d_in[14];
    const float* box_b = (const float*)d_in[15];
    const float* encf_W = (const float*)d_in[16];
    const float* encf_b = (const float*)d_in[17];
    const float* decf_W = (const float*)d_in[18];
    const float* decf_b = (const float*)d_in[19];
    const float* out_W = (const float*)d_in[20];
    const float* out_b = (const float*)d_in[21];
    const float* enc_Wih = (const float*)d_in[22];  // [2,384,128]
    const float* enc_Whh = (const float*)d_in[23];
    const float* enc_bih = (const float*)d_in[24];  // [2,384]
    const float* enc_bhh = (const float*)d_in[25];
    const float* dec_Wih = (const float*)d_in[26];
    const float* dec_Whh = (const float*)d_in[27];
    const float* dec_bih = (const float*)d_in[28];
    const float* dec_bhh = (const float*)d_in[29];

    float* out = (float*)d_out;
    float* W = (float*)d_ws;

    // workspace layout (floats)
    const size_t o_cat = 0;                           // [8160,384] enc cat / [8160,192] dec cat
    const size_t o_t1  = o_cat + (size_t)NN * 384;    // [8160,512]
    const size_t o_all = o_t1  + (size_t)NN * 512;    // [8160,128]
    const size_t o_gx  = o_all + (size_t)NN * 128;    // [8160,768]  (fwd|bwd gates)
    const size_t o_ysf = o_gx  + (size_t)NN * 768;    // [8160,128]
    const size_t o_ysb = o_ysf + (size_t)NN * 128;    // [8160,128]
    const size_t o_h   = o_ysb + (size_t)NN * 128;    // [2,128]

    float* cat  = W + o_cat;
    float* t1   = W + o_t1;
    float* allb = W + o_all;
    float* gx   = W + o_gx;
    float* ysf  = W + o_ysf;
    float* ysb  = W + o_ysb;
    float* hfin = W + o_h;

    const int M = NN;
    dim3 blk(256);
    auto grid_for = [](int m, int n) { return dim3((m + 63) / 64, n / 64); };

    // ---- encoder feature pipeline ----
    gemm_nt<true ><<<grid_for(M, 128), blk, 0, stream>>>(boxes_feature, 1024, appear_W, appear_b, cat + 0,   384, M, 128, 1024);
    gemm_nt<true ><<<grid_for(M, 512), blk, 0, stream>>>(boxes_score,   2560, s1_W,     s1_b,     t1,        512, M, 512, 2560);
    gemm_nt<true ><<<grid_for(M, 128), blk, 0, stream>>>(t1,            512,  s2_W,     s2_b,     cat + 128, 384, M, 128, 512);
    gemm_nt<true ><<<grid_for(M, 128), blk, 0, stream>>>(boxes_box,     320,  box_W,    box_b,    cat + 256, 384, M, 128, 320);
    gemm_nt<true ><<<grid_for(M, 128), blk, 0, stream>>>(cat,           384,  encf_W,   encf_b,   allb,      128, M, 128, 384);
    // gx for both directions in one GEMM (Wih[2] rows are contiguous -> N=768)
    gemm_nt<false><<<grid_for(M, 768), blk, 0, stream>>>(allb,          128,  enc_Wih,  enc_bih,  gx,        768, M, 768, 128);

    // ---- encoder recurrence: 2 blocks (fwd, bwd), writes hf|hb ----
    gru_seq<<<dim3(2), dim3(768), 0, stream>>>(gx, gx + 384, 768,
                                               enc_Whh, enc_bhh,
                                               nullptr, nullptr, hfin,
                                               nullptr, nullptr, M);

    // ---- decoder feature pipeline (reuses cat/allb/gx regions) ----
    gemm_nt<true ><<<grid_for(M, 128), blk, 0, stream>>>(ac_feature, 1024, appear_W, appear_b, cat, 192, M, 128, 1024);
    copy_scorebox<<<dim3((M * 64 + 255) / 256), dim3(256), 0, stream>>>(ac_score, ac_box, cat, M);
    gemm_nt<true ><<<grid_for(M, 128), blk, 0, stream>>>(cat,  192, decf_W,  decf_b,  allb, 128, M, 128, 192);
    gemm_nt<false><<<grid_for(M, 768), blk, 0, stream>>>(allb, 128, dec_Wih, dec_bih, gx,   768, M, 768, 128);

    // ---- decoder recurrence: 80 segments x 2 dirs, writes ys ----
    gru_seq<<<dim3(2 * NCLS), dim3(768), 0, stream>>>(gx, gx + 384, 768,
                                                      dec_Whh, dec_bhh,
                                                      ucl, hfin, nullptr,
                                                      ysf, ysb, M);

    // ---- output projection + sigmoid ----
    out_kernel<<<dim3(M), dim3(64), 0, stream>>>(ysf, ysb, out_W, out_b, out, M);

    (void)in_sizes; (void)n_in; (void)out_size; (void)ws_size;
}

// Round 2
// 6247.491 us; speedup vs baseline: 1.3725x; 1.3725x over previous
//
#include <hip/hip_runtime.h>
#include <hip/hip_bf16.h>
#include <cstddef>

// Problem constants (fixed by the reference)
#define NN 8160     // encoder rows
#define MM 8160     // decoder rows
#define HH 128      // hidden
#define NCLS 80

typedef float v2f __attribute__((ext_vector_type(2)));

// ---------------------------------------------------------------------------
// Generic GEMM: C[m,n] = act(dot(A[m,0:K], W[n,0:K]) + bias[n])
// ---------------------------------------------------------------------------
template<bool RELU>
__global__ __launch_bounds__(256) void gemm_nt(
    const float* __restrict__ A, int lda,
    const float* __restrict__ W, const float* __restrict__ bias,
    float* __restrict__ C, int ldc,
    int M, int N, int K)
{
    __shared__ __align__(16) float As[64][36];   // [m][k], padded stride 36
    __shared__ __align__(16) float Wt[32][68];   // [k][n], padded stride 68

    const int tid = threadIdx.x;
    const int tx = tid & 15, ty = tid >> 4;
    const int m0 = blockIdx.x * 64, n0 = blockIdx.y * 64;
    const int lr = tid >> 3;     // 0..31
    const int lc = tid & 7;      // float4 col 0..7 (k = lc*4)

    float acc[4][4] = {};

    for (int k0 = 0; k0 < K; k0 += 32) {
        #pragma unroll
        for (int rr = 0; rr < 2; rr++) {
            int r = lr + rr * 32;
            int gm = m0 + r;
            float4 v = make_float4(0.f, 0.f, 0.f, 0.f);
            if (gm < M) v = *(const float4*)&A[(size_t)gm * lda + k0 + lc * 4];
            *(float4*)&As[r][lc * 4] = v;
        }
        #pragma unroll
        for (int rr = 0; rr < 2; rr++) {
            int r = lr + rr * 32;  // n-local
            float4 v = *(const float4*)&W[(size_t)(n0 + r) * K + k0 + lc * 4];
            Wt[lc * 4 + 0][r] = v.x;
            Wt[lc * 4 + 1][r] = v.y;
            Wt[lc * 4 + 2][r] = v.z;
            Wt[lc * 4 + 3][r] = v.w;
        }
        __syncthreads();

        #pragma unroll
        for (int k4 = 0; k4 < 8; k4++) {
            float4 a4[4], w4[4];
            #pragma unroll
            for (int i = 0; i < 4; i++)
                a4[i] = *(const float4*)&As[ty * 4 + i][k4 * 4];
            #pragma unroll
            for (int kk = 0; kk < 4; kk++)
                w4[kk] = *(const float4*)&Wt[k4 * 4 + kk][tx * 4];
            #pragma unroll
            for (int i = 0; i < 4; i++) {
                acc[i][0] += a4[i].x * w4[0].x + a4[i].y * w4[1].x + a4[i].z * w4[2].x + a4[i].w * w4[3].x;
                acc[i][1] += a4[i].x * w4[0].y + a4[i].y * w4[1].y + a4[i].z * w4[2].y + a4[i].w * w4[3].y;
                acc[i][2] += a4[i].x * w4[0].z + a4[i].y * w4[1].z + a4[i].z * w4[2].z + a4[i].w * w4[3].z;
                acc[i][3] += a4[i].x * w4[0].w + a4[i].y * w4[1].w + a4[i].z * w4[2].w + a4[i].w * w4[3].w;
            }
        }
        __syncthreads();
    }

    #pragma unroll
    for (int i = 0; i < 4; i++) {
        int gm = m0 + ty * 4 + i;
        if (gm >= M) continue;
        #pragma unroll
        for (int j = 0; j < 4; j++) {
            int gn = n0 + tx * 4 + j;
            float v = acc[i][j] + bias[gn];
            if (RELU) v = v > 0.f ? v : 0.f;
            C[(size_t)gm * ldc + gn] = v;
        }
    }
}

// ---------------------------------------------------------------------------
__global__ void copy_scorebox(const float* __restrict__ acs,
                              const float* __restrict__ acb,
                              float* __restrict__ cat, int M)
{
    int i = blockIdx.x * blockDim.x + threadIdx.x;
    if (i >= M * 64) return;
    int m = i >> 6, c = i & 63;
    float v = (c < 32) ? acs[m * 32 + c] : acb[m * 32 + (c - 32)];
    cat[(size_t)m * 192 + 128 + c] = v;
}

// ---------------------------------------------------------------------------
// VALU-only cross-lane reduction primitives (gfx950)
// ---------------------------------------------------------------------------
__device__ __forceinline__ float swap32_add(float a, float b) {
    // after swap: a+b = value reduced across lane^32; lanes<32 hold a's row,
    // lanes>=32 hold b's row
    asm("v_permlane32_swap_b32 %0, %1" : "+v"(a), "+v"(b));
    return a + b;
}
__device__ __forceinline__ float swap16_add(float a, float b) {
    asm("v_permlane16_swap_b32 %0, %1" : "+v"(a), "+v"(b));
    return a + b;
}
template<int CTRL>
__device__ __forceinline__ float dpp_add(float x) {
    int xi = __builtin_bit_cast(int, x);
    int yi = __builtin_amdgcn_update_dpp(0, xi, CTRL, 0xF, 0xF, true);
    return x + __builtin_bit_cast(float, yi);
}
// quad_perm encodings: xor1 = [1,0,3,2] = 0xB1; xor2 = [2,3,0,1] = 0x4E

__device__ __forceinline__ void pk_fma(v2f& acc, v2f a, v2f b) {
    asm("v_pk_fma_f32 %0, %1, %2, %0" : "+v"(acc) : "v"(a), "v"(b));
}

// ---------------------------------------------------------------------------
// Sequential GRU (PyTorch gate semantics), batch=1. 768 threads = 12 waves.
// Thread (wave w, lane l): k-chunk c = bits{0,1,4,5}(l) (8 floats of h),
// row group g = bits{2,3}(l); thread computes 8 partial dots for rows
// w*32+g*8+0..7. VALU butterfly over lane bits {5,4,1,0} leaves the full dot
// for row rid = bit1 + 2*bit4 + 4*bit5 on each lane (dup across bit0).
// Waves 0-3: r-gate rows, 4-7: z, 8-11: n. Phase A writes sigmoids to LDS;
// phase B (n-waves) combines and updates h.
// ---------------------------------------------------------------------------
__global__ __launch_bounds__(768) void gru_seq(
    const float* __restrict__ gx_f, const float* __restrict__ gx_b, int gx_ld,
    const float* __restrict__ Whh,   // [2,384,128]
    const float* __restrict__ bhh,   // [2,384]
    const int*   __restrict__ seglen,
    const float* __restrict__ h_init,  // [2,128] or null (zeros)
    float* __restrict__ h_final,       // [2,128] or null
    float* __restrict__ ys_f, float* __restrict__ ys_b,  // [M,128] or null
    int M)
{
    int dir, start, end;
    if (seglen) {
        dir = blockIdx.x & 1;
        int seg = blockIdx.x >> 1;
        start = seglen[seg];
        end = seglen[seg + 1];
    } else {
        dir = blockIdx.x;
        start = 0;
        end = M;
    }
    const int T = end - start;
    const float* gx = dir ? gx_b : gx_f;
    float* ys = dir ? ys_b : ys_f;

    const int t = threadIdx.x;
    const int w = t >> 6;                 // wave 0..11
    const int l = t & 63;
    const int g = (l >> 2) & 3;           // row group in wave
    const int c = (l & 3) | (((l >> 4) & 3) << 2);  // k-chunk 0..15
    const int rid = ((l >> 1) & 1) | (((l >> 4) & 1) << 1) | (((l >> 5) & 1) << 2);
    const int myrow = w * 32 + g * 8 + rid;  // 0..383 (row whose dot this lane ends with)

    __shared__ __align__(16) float h_s[128];
    __shared__ float rg_s[128], z_s[128];

    // preload 8 rows x 8 k of Whh into registers as float2 pairs
    v2f wr[8][4];
    const float* wbase = Whh + ((size_t)dir * 384 + w * 32 + g * 8) * 128 + c * 8;
    #pragma unroll
    for (int i = 0; i < 8; i++) {
        float4 q0 = *(const float4*)(wbase + (size_t)i * 128);
        float4 q1 = *(const float4*)(wbase + (size_t)i * 128 + 4);
        wr[i][0] = (v2f){q0.x, q0.y};
        wr[i][1] = (v2f){q0.z, q0.w};
        wr[i][2] = (v2f){q1.x, q1.y};
        wr[i][3] = (v2f){q1.z, q1.w};
    }
    const float bh = bhh[dir * 384 + myrow];

    if (t < 128) h_s[t] = h_init ? h_init[dir * 128 + t] : 0.f;
    __syncthreads();

    if (T > 0) {
        const int trow0 = dir ? (end - 1) : start;
        const ptrdiff_t gstep = dir ? -(ptrdiff_t)gx_ld : (ptrdiff_t)gx_ld;
        const float* gxp = gx + (size_t)trow0 * gx_ld + myrow;
        float gxv = *gxp;

        for (int s = 0; s < T; s++) {
            const float gx_next = (s + 1 < T) ? gxp[gstep] : 0.f;  // prefetch
            const int trow = dir ? (end - 1 - s) : (start + s);

            // h chunk: 8 floats
            const float4 hv0 = *(const float4*)&h_s[c * 8];
            const float4 hv1 = *(const float4*)&h_s[c * 8 + 4];
            v2f ha[4];
            ha[0] = (v2f){hv0.x, hv0.y}; ha[1] = (v2f){hv0.z, hv0.w};
            ha[2] = (v2f){hv1.x, hv1.y}; ha[3] = (v2f){hv1.z, hv1.w};

            v2f acc[8];
            #pragma unroll
            for (int i = 0; i < 8; i++) acc[i] = (v2f){0.f, 0.f};
            #pragma unroll
            for (int i = 0; i < 8; i++) {
                #pragma unroll
                for (int k2 = 0; k2 < 4; k2++) pk_fma(acc[i], wr[i][k2], ha[k2]);
            }
            float p[8];
            #pragma unroll
            for (int i = 0; i < 8; i++) p[i] = acc[i][0] + acc[i][1];

            // butterfly over lane bits {5,4,1,0}, all VALU
            float s0 = swap32_add(p[0], p[4]);
            float s1 = swap32_add(p[1], p[5]);
            float s2 = swap32_add(p[2], p[6]);
            float s3 = swap32_add(p[3], p[7]);
            float t0 = swap16_add(s0, s2);
            float t1 = swap16_add(s1, s3);
            float u0 = dpp_add<0x4E>(t0);   // + lane^2
            float u1 = dpp_add<0x4E>(t1);
            float vsel = (l & 2) ? u1 : u0;
            const float dot = dpp_add<0xB1>(vsel);  // + lane^1 (dup reduce)

            // phase A: r/z gates -> LDS
            if (myrow < 256) {
                float pre = dot + bh + gxv;
                float sig = 1.f / (1.f + __expf(-pre));
                if (!(l & 1)) {
                    if (myrow < 128) rg_s[myrow] = sig;
                    else             z_s[myrow - 128] = sig;
                }
            }
            __syncthreads();

            // phase B: n gate + state update
            if (myrow >= 256) {
                const int j = myrow - 256;
                const float rg = rg_s[j];
                const float z  = z_s[j];
                const float hn_pre = dot + bh;
                const float narg = gxv + rg * hn_pre;
                const float n = 1.f - 2.f / (1.f + __expf(2.f * narg));  // tanh
                const float hnew = (1.f - z) * n + z * h_s[j];
                if (!(l & 1)) {
                    h_s[j] = hnew;
                    if (ys) ys[(size_t)trow * 128 + j] = hnew;
                }
            }
            __syncthreads();

            gxv = gx_next;
            gxp += gstep;
        }
    }

    if (h_final && t < 128) h_final[dir * 128 + t] = h_s[t];
}

// ---------------------------------------------------------------------------
__global__ __launch_bounds__(64) void out_kernel(
    const float* __restrict__ ysf, const float* __restrict__ ysb,
    const float* __restrict__ ow, const float* __restrict__ ob,
    float* __restrict__ out, int M)
{
    const int m = blockIdx.x;
    const int l = threadIdx.x;  // 0..63
    const float* f = ysf + (size_t)m * 128;
    const float* b = ysb + (size_t)m * 128;
    float s = f[l] * ow[l] + f[l + 64] * ow[l + 64]
            + b[l] * ow[128 + l] + b[l + 64] * ow[192 + l];
    #pragma unroll
    for (int o = 32; o >= 1; o >>= 1) s += __shfl_xor(s, o, 64);
    if (l == 0) out[m] = 1.f / (1.f + __expf(-(s + ob[0])));
}

// ---------------------------------------------------------------------------
extern "C" void kernel_launch(void* const* d_in, const int* in_sizes, int n_in,
                              void* d_out, int out_size, void* d_ws, size_t ws_size,
                              hipStream_t stream)
{
    const float* boxes_feature = (const float*)d_in[0];   // [N,1024]
    const float* boxes_score   = (const float*)d_in[1];   // [N,2560]
    const float* boxes_box     = (const float*)d_in[2];   // [N,320]
    const float* ac_feature    = (const float*)d_in[3];   // [M,1024]
    const float* ac_score      = (const float*)d_in[4];   // [M,32]
    const float* ac_box        = (const float*)d_in[5];   // [M,32]
    const int*   ucl           = (const int*)d_in[7];     // [81]
    const float* appear_W = (const float*)d_in[8];
    const float* appear_b = (const float*)d_in[9];
    const float* s1_W = (const float*)d_in[10];
    const float* s1_b = (const float*)d_in[11];
    const float* s2_W = (const float*)d_in[12];
    const float* s2_b = (const float*)d_in[13];
    const float* box_W = (const float*)d_in[14];
    const float* box_b = (const float*)d_in[15];
    const float* encf_W = (const float*)d_in[16];
    const float* encf_b = (const float*)d_in[17];
    const float* decf_W = (const float*)d_in[18];
    const float* decf_b = (const float*)d_in[19];
    const float* out_W = (const float*)d_in[20];
    const float* out_b = (const float*)d_in[21];
    const float* enc_Wih = (const float*)d_in[22];  // [2,384,128]
    const float* enc_Whh = (const float*)d_in[23];
    const float* enc_bih = (const float*)d_in[24];  // [2,384]
    const float* enc_bhh = (const float*)d_in[25];
    const float* dec_Wih = (const float*)d_in[26];
    const float* dec_Whh = (const float*)d_in[27];
    const float* dec_bih = (const float*)d_in[28];
    const float* dec_bhh = (const float*)d_in[29];

    float* out = (float*)d_out;
    float* W = (float*)d_ws;

    // workspace layout (floats)
    const size_t o_cat = 0;                           // [8160,384] enc cat / [8160,192] dec cat
    const size_t o_t1  = o_cat + (size_t)NN * 384;    // [8160,512]
    const size_t o_all = o_t1  + (size_t)NN * 512;    // [8160,128]
    const size_t o_gx  = o_all + (size_t)NN * 128;    // [8160,768]  (fwd|bwd gates)
    const size_t o_ysf = o_gx  + (size_t)NN * 768;    // [8160,128]
    const size_t o_ysb = o_ysf + (size_t)NN * 128;    // [8160,128]
    const size_t o_h   = o_ysb + (size_t)NN * 128;    // [2,128]

    float* cat  = W + o_cat;
    float* t1   = W + o_t1;
    float* allb = W + o_all;
    float* gx   = W + o_gx;
    float* ysf  = W + o_ysf;
    float* ysb  = W + o_ysb;
    float* hfin = W + o_h;

    const int M = NN;
    dim3 blk(256);
    auto grid_for = [](int m, int n) { return dim3((m + 63) / 64, n / 64); };

    // ---- encoder feature pipeline ----
    gemm_nt<true ><<<grid_for(M, 128), blk, 0, stream>>>(boxes_feature, 1024, appear_W, appear_b, cat + 0,   384, M, 128, 1024);
    gemm_nt<true ><<<grid_for(M, 512), blk, 0, stream>>>(boxes_score,   2560, s1_W,     s1_b,     t1,        512, M, 512, 2560);
    gemm_nt<true ><<<grid_for(M, 128), blk, 0, stream>>>(t1,            512,  s2_W,     s2_b,     cat + 128, 384, M, 128, 512);
    gemm_nt<true ><<<grid_for(M, 128), blk, 0, stream>>>(boxes_box,     320,  box_W,    box_b,    cat + 256, 384, M, 128, 320);
    gemm_nt<true ><<<grid_for(M, 128), blk, 0, stream>>>(cat,           384,  encf_W,   encf_b,   allb,      128, M, 128, 384);
    gemm_nt<false><<<grid_for(M, 768), blk, 0, stream>>>(allb,          128,  enc_Wih,  enc_bih,  gx,        768, M, 768, 128);

    // ---- encoder recurrence: 2 blocks (fwd, bwd), writes hf|hb ----
    gru_seq<<<dim3(2), dim3(768), 0, stream>>>(gx, gx + 384, 768,
                                               enc_Whh, enc_bhh,
                                               nullptr, nullptr, hfin,
                                               nullptr, nullptr, M);

    // ---- decoder feature pipeline ----
    gemm_nt<true ><<<grid_for(M, 128), blk, 0, stream>>>(ac_feature, 1024, appear_W, appear_b, cat, 192, M, 128, 1024);
    copy_scorebox<<<dim3((M * 64 + 255) / 256), dim3(256), 0, stream>>>(ac_score, ac_box, cat, M);
    gemm_nt<true ><<<grid_for(M, 128), blk, 0, stream>>>(cat,  192, decf_W,  decf_b,  allb, 128, M, 128, 192);
    gemm_nt<false><<<grid_for(M, 768), blk, 0, stream>>>(allb, 128, dec_Wih, dec_bih, gx,   768, M, 768, 128);

    // ---- decoder recurrence: 80 segments x 2 dirs, writes ys ----
    gru_seq<<<dim3(2 * NCLS), dim3(768), 0, stream>>>(gx, gx + 384, 768,
                                                      dec_Whh, dec_bhh,
                                                      ucl, hfin, nullptr,
                                                      ysf, ysb, M);

    // ---- output projection + sigmoid ----
    out_kernel<<<dim3(M), dim3(64), 0, stream>>>(ysf, ysb, out_W, out_b, out, M);

    (void)in_sizes; (void)n_in; (void)out_size; (void)ws_size;
}